// Round 7
// baseline (1204.175 us; speedup 1.0000x reference)
//
#include <hip/hip_runtime.h>
#include <cstdint>
#include <cstddef>

using u16 = unsigned short;
using u32 = unsigned int;

typedef __attribute__((ext_vector_type(8))) short bf16x8;
typedef __attribute__((ext_vector_type(4))) float f32x4;

__device__ __forceinline__ u16 f2bf(float f) {
  union { float f; u32 u; } v; v.f = f;
  u32 r = v.u + 0x7FFFu + ((v.u >> 16) & 1u);
  return (u16)(r >> 16);
}
__device__ __forceinline__ float bf2f(u16 h) {
  union { u32 u; float f; } v; v.u = ((u32)h) << 16;
  return v.f;
}

__device__ __forceinline__ void gl_lds16(const void* g, void* l) {
  __builtin_amdgcn_global_load_lds(
      (const __attribute__((address_space(1))) void*)g,
      (__attribute__((address_space(3))) void*)l, 16, 0, 0);
}

// ---------------- fp32 -> bf16 weight convert (optionally zero-padded) ---
__global__ __launch_bounds__(256) void k_f2bf(const float* __restrict__ s,
                                              u16* __restrict__ d, int n,
                                              int npad) {
  int i = blockIdx.x * 256 + threadIdx.x;
  if (i < npad) d[i] = (i < n) ? f2bf(s[i]) : (u16)0;
}

// ---------------- combined rel-bias + shift-mask + pad tables ------------
// tbl[((h*4+wt))*4096 + j*64 + i]; wt = 2*(wh==7) + (ww==7); j>=49 -> -3e38
__global__ __launch_bounds__(256) void k_tbl(const float* __restrict__ relt,
                                             float* __restrict__ tbl) {
  int id = blockIdx.x * 256 + threadIdx.x;
  if (id >= 196608) return;
  int i = id & 63, j = (id >> 6) & 63;
  int wt = (id >> 12) & 3, h = id >> 14;
  float v;
  if (j >= 49) {
    v = -3e38f;
  } else {
    int ii = i < 49 ? i : 48;
    int r1 = ii / 7, c1 = ii % 7, r2 = j / 7, c2 = j % 7;
    v = relt[((r1 - r2 + 6) * 13 + (c1 - c2 + 6)) * 12 + h];
    int rr1 = (wt & 2) ? (r1 < 4 ? 1 : 2) : 0;
    int rr2 = (wt & 2) ? (r2 < 4 ? 1 : 2) : 0;
    int cc1 = (wt & 1) ? (c1 < 4 ? 1 : 2) : 0;
    int cc2 = (wt & 1) ? (c2 < 4 ? 1 : 2) : 0;
    if (rr1 != rr2 || cc1 != cc2) v -= 100.f;
  }
  tbl[id] = v;
}

// ---------------- LayerNorm (optionally fused shift+window gather) -------
template <int GATHER>
__global__ __launch_bounds__(256) void k_ln(const float* __restrict__ x,
                                            const float* __restrict__ g,
                                            const float* __restrict__ b,
                                            u16* __restrict__ out) {
  int wave = threadIdx.x >> 6, lane = threadIdx.x & 63;
  int idx = blockIdx.x * 4 + wave;  // output token index
  int src;
  if (GATHER) {
    int n = idx / 49, l = idx % 49;
    int bb = n >> 6, wi = n & 63;
    int wh = wi >> 3, ww = wi & 7;
    int r = l / 7, c = l % 7;
    int sr = wh * 7 + r + 3; if (sr >= 56) sr -= 56;
    int sc = ww * 7 + c + 3; if (sc >= 56) sc -= 56;
    src = bb * 3136 + sr * 56 + sc;
  } else {
    src = idx;
  }
  const float* xi = x + (size_t)src * 384;
  float2 v[3];
  float s = 0.f, sq = 0.f;
#pragma unroll
  for (int p = 0; p < 3; ++p) {
    v[p] = *(const float2*)(xi + p * 128 + lane * 2);
    s += v[p].x + v[p].y;
    sq += v[p].x * v[p].x + v[p].y * v[p].y;
  }
#pragma unroll
  for (int o = 32; o; o >>= 1) {
    s += __shfl_xor(s, o);
    sq += __shfl_xor(sq, o);
  }
  float mu = s * (1.f / 384.f);
  float var = sq * (1.f / 384.f) - mu * mu;
  float rstd = rsqrtf(var + 1e-5f);
  u16* oo = out + (size_t)idx * 384;
#pragma unroll
  for (int p = 0; p < 3; ++p) {
    int e = p * 128 + lane * 2;
    u16 o0 = f2bf((v[p].x - mu) * rstd * g[e] + b[e]);
    u16 o1 = f2bf((v[p].y - mu) * rstd * g[e + 1] + b[e + 1]);
    u32 pk = (u32)o0 | ((u32)o1 << 16);
    *(u32*)(oo + e) = pk;
  }
}

// ---------------- GEMM v3: 256x256 tile, 8 waves, BK=64, 8-phase ----------
// m201-style schedule: per phase {ds_read subtile || stage 1 half-tile} ->
// barrier -> lgkmcnt(0) -> 16-MFMA cluster (setprio) -> barrier. Counted
// vmcnt(4) once per K-tile (never 0 mid-loop). T2 XOR-swizzle both-sides.
// Half-tile mapping: ph0/ph1 stage (t+1) A-lo/A-hi into A[b^1] (free since
// ph3(t-1)); ph2/ph3 stage (t+2) B-lo/B-hi into B[b] (B[b] only read at ph0).
enum { EPI_QKV = 0, EPI_PROJ = 1, EPI_GELU = 2, EPI_FC2 = 3 };

#define DO_PHASE(q, STAGE_STMT, WAIT_STMT)                                     \
  {                                                                            \
    bf16x8 afr[2][2];                                                          \
    _Pragma("unroll") for (int i = 0; i < 2; ++i)                              \
        _Pragma("unroll") for (int kh = 0; kh < 2; ++kh)                       \
            afr[i][kh] = *(const bf16x8*)(&Ab[(wr * 128 + ((q)*2 + i) * 16 +   \
                                              lrow) * 64 +                     \
                                             ((kh * 32 + g8) ^ rx)]);          \
    STAGE_STMT;                                                                \
    WAIT_STMT;                                                                 \
    asm volatile("" ::: "memory");                                             \
    __builtin_amdgcn_s_barrier();                                              \
    asm volatile("s_waitcnt lgkmcnt(0)" ::: "memory");                         \
    __builtin_amdgcn_s_setprio(1);                                             \
    _Pragma("unroll") for (int i = 0; i < 2; ++i)                              \
        _Pragma("unroll") for (int n = 0; n < 4; ++n)                          \
            _Pragma("unroll") for (int kh = 0; kh < 2; ++kh)                   \
                acc[(q)*2 + i][n] = __builtin_amdgcn_mfma_f32_16x16x32_bf16(   \
                    afr[i][kh], bfr[n][kh], acc[(q)*2 + i][n], 0, 0, 0);       \
    __builtin_amdgcn_s_setprio(0);                                             \
    asm volatile("" ::: "memory");                                             \
    __builtin_amdgcn_s_barrier();                                              \
    asm volatile("" ::: "memory");                                             \
  }

template <int EPI>
__global__ __launch_bounds__(512, 2) void k_gemm8(
    const u16* __restrict__ A, const u16* __restrict__ Bw,
    const float* __restrict__ bias, u16* __restrict__ obf,
    float* __restrict__ of32, const float* __restrict__ addsrc,
    int K, int lda, int ldb, int ldc, int NT, int Nmax) {
  __shared__ u16 As[2][256 * 64];
  __shared__ u16 Bs[2][256 * 64];
  // bijective XCD chunk swizzle (m204), n-inner for A-panel L2 reuse
  const int nwg = gridDim.x;
  const int q = nwg >> 3, r = nwg & 7;
  const int xcd = blockIdx.x & 7, rank = blockIdx.x >> 3;
  const int swz = (xcd < r ? xcd * (q + 1) : r * (q + 1) + (xcd - r) * q) + rank;
  const int m0 = (swz / NT) * 256, n0 = (swz % NT) * 256;

  const int tid = threadIdx.x;
  const int wid = tid >> 6, lane = tid & 63;
  const int wr = wid >> 2, wc = wid & 3;  // 2M x 4N waves, per-wave 128x64

  // staging: pre-swizzled global source; linear LDS dest (HW adds lane*16B)
  const int srow = tid >> 3;                      // 0..63
  const int scol = 8 * ((tid & 7) ^ (srow & 7));  // inverse-swizzled col
  auto STAGE = [&](u16* dst, const u16* src, int ld, int row0, int half,
                   int k0) {
#pragma unroll
    for (int j = 0; j < 2; ++j)
      gl_lds16(src + (size_t)(row0 + half * 128 + j * 64 + srow) * ld + k0 +
                   scol,
               dst + half * 8192 + j * 4096 + wid * 512);
  };

  f32x4 acc[8][4] = {};
  const int lrow = lane & 15;
  const int g8 = (lane >> 4) * 8;
  const int rx = (lrow & 7) << 3;  // read-side XOR (u16 units)

  const int NTK = K >> 6;  // >= 2 for all call sites

  // prologue: tile0 all 4 halves + tile1 B halves; vmcnt(4) -> tile0 ready
  STAGE(As[0], A, lda, m0, 0, 0);
  STAGE(As[0], A, lda, m0, 1, 0);
  STAGE(Bs[0], Bw, ldb, n0, 0, 0);
  STAGE(Bs[0], Bw, ldb, n0, 1, 0);
  if (NTK > 1) {
    STAGE(Bs[1], Bw, ldb, n0, 0, 64);
    STAGE(Bs[1], Bw, ldb, n0, 1, 64);
    asm volatile("s_waitcnt vmcnt(4)" ::: "memory");
  } else {
    asm volatile("s_waitcnt vmcnt(0)" ::: "memory");
  }
  asm volatile("" ::: "memory");
  __builtin_amdgcn_s_barrier();
  asm volatile("" ::: "memory");

  for (int t = 0; t < NTK; ++t) {
    const int b = t & 1;
    u16* Ab = As[b];
    u16* Bb = Bs[b];
    // B fragments for this K-tile (read once, held across phases)
    bf16x8 bfr[4][2];
#pragma unroll
    for (int n = 0; n < 4; ++n)
#pragma unroll
      for (int kh = 0; kh < 2; ++kh)
        bfr[n][kh] = *(const bf16x8*)(&Bb[(wc * 64 + n * 16 + lrow) * 64 +
                                          ((kh * 32 + g8) ^ rx)]);
    DO_PHASE(0,
             if (t + 1 < NTK) STAGE(As[b ^ 1], A, lda, m0, 0, (t + 1) << 6),
             ((void)0));
    DO_PHASE(1,
             if (t + 1 < NTK) STAGE(As[b ^ 1], A, lda, m0, 1, (t + 1) << 6),
             ((void)0));
    DO_PHASE(2,
             if (t + 2 < NTK) STAGE(Bs[b], Bw, ldb, n0, 0, (t + 2) << 6),
             ((void)0));
    DO_PHASE(3,
             if (t + 2 < NTK) STAGE(Bs[b], Bw, ldb, n0, 1, (t + 2) << 6),
             {
               if (t + 2 < NTK)
                 asm volatile("s_waitcnt vmcnt(4)" ::: "memory");
               else if (t + 1 < NTK)
                 asm volatile("s_waitcnt vmcnt(0)" ::: "memory");
             });
  }

  // epilogue: D mapping col=lane&15, row=(lane>>4)*4+reg
  const int erow = (lane >> 4) * 4;
  const int ecol = lane & 15;
#pragma unroll
  for (int mi = 0; mi < 8; ++mi) {
#pragma unroll
    for (int ni = 0; ni < 4; ++ni) {
      int gcol = n0 + wc * 64 + ni * 16 + ecol;
      if (gcol >= Nmax) continue;  // padded-N guard
      float bv = bias[gcol];
#pragma unroll
      for (int r4 = 0; r4 < 4; ++r4) {
        int grow = m0 + wr * 128 + mi * 16 + erow + r4;
        float v = acc[mi][ni][r4] + bv;
        if (EPI == EPI_QKV) {
          // fold attention scale 1/sqrt(32) into q columns (cols < 384)
          float vv = (gcol < 384) ? v * 0.17677669529663689f : v;
          obf[(size_t)grow * ldc + gcol] = f2bf(vv);
        } else if (EPI == EPI_GELU) {
          float gl = 0.5f * v * (1.f + erff(v * 0.70710678118f));
          obf[(size_t)grow * ldc + gcol] = f2bf(gl);
        } else if (EPI == EPI_PROJ) {
          int nwin = grow / 49, l = grow % 49;
          int bb = nwin >> 6, wi = nwin & 63;
          int wh = wi >> 3, ww = wi & 7;
          int rr = l / 7, cc = l % 7;
          int sr = wh * 7 + rr + 3; if (sr >= 56) sr -= 56;
          int sc = ww * 7 + cc + 3; if (sc >= 56) sc -= 56;
          size_t idx = ((size_t)(bb * 3136 + sr * 56 + sc)) * 384 + gcol;
          of32[idx] = addsrc[idx] + v;
        } else {  // EPI_FC2: accumulate into (row-chunked) d_out
          size_t idx = (size_t)grow * 384 + gcol;
          of32[idx] = of32[idx] + v;
        }
      }
    }
  }
}

// ---------------- MFMA windowed attention v2 ------------------------------
__global__ __launch_bounds__(64) void k_attn2(const u16* __restrict__ qkv,
                                              const float* __restrict__ tbl,
                                              u16* __restrict__ out) {
  __shared__ u16 P[64 * 64];  // 8KB, wave-private
  const int bx = blockIdx.x;
  const int n = bx / 12, h = bx - n * 12;
  const int lane = threadIdx.x & 63;
  const int g = lane >> 4, c = lane & 15;
  const u16* base = qkv + (size_t)n * 56448 + h * 32;
  const int wi = n & 63;
  const int wt = (((wi >> 3) == 7) ? 2 : 0) | (((wi & 7) == 7) ? 1 : 0);
  const float* T = tbl + (size_t)((h << 2) | wt) * 4096;

  f32x4 st[4][4];  // [kj][qi]; reg r -> j = kj*16+g*4+r, i = qi*16+c
#pragma unroll
  for (int kj = 0; kj < 4; ++kj)
#pragma unroll
    for (int qi = 0; qi < 4; ++qi)
#pragma unroll
      for (int r = 0; r < 4; ++r)
        st[kj][qi][r] = T[(kj * 16 + g * 4 + r) * 64 + qi * 16 + c];

  bf16x8 qf[4], kf[4];
#pragma unroll
  for (int t = 0; t < 4; ++t) {
    int row = t * 16 + c; if (row > 48) row = 48;
    qf[t] = *(const bf16x8*)(base + (size_t)row * 1152 + g * 8);
    kf[t] = *(const bf16x8*)(base + (size_t)row * 1152 + 384 + g * 8);
  }

#pragma unroll
  for (int kj = 0; kj < 4; ++kj)
#pragma unroll
    for (int qi = 0; qi < 4; ++qi)
      st[kj][qi] = __builtin_amdgcn_mfma_f32_16x16x32_bf16(kf[kj], qf[qi],
                                                           st[kj][qi], 0, 0, 0);

#pragma unroll
  for (int qi = 0; qi < 4; ++qi) {
    float m = -3e38f;
#pragma unroll
    for (int kj = 0; kj < 4; ++kj)
#pragma unroll
      for (int r = 0; r < 4; ++r) m = fmaxf(m, st[kj][qi][r]);
    m = fmaxf(m, __shfl_xor(m, 16));
    m = fmaxf(m, __shfl_xor(m, 32));
    float sum = 0.f;
#pragma unroll
    for (int kj = 0; kj < 4; ++kj)
#pragma unroll
      for (int r = 0; r < 4; ++r) {
        float e = __expf(st[kj][qi][r] - m);
        st[kj][qi][r] = e;
        sum += e;
      }
    sum += __shfl_xor(sum, 16);
    sum += __shfl_xor(sum, 32);
    float inv = 1.f / sum;
    int i = qi * 16 + c;
#pragma unroll
    for (int kj = 0; kj < 4; ++kj)
#pragma unroll
      for (int hh = 0; hh < 2; ++hh) {
        u32 pk = (u32)f2bf(st[kj][qi][2 * hh] * inv) |
                 ((u32)f2bf(st[kj][qi][2 * hh + 1] * inv) << 16);
        int idx = (i * 64 + kj * 16 + g * 4 + 2 * hh) ^ ((i & 7) << 3);
        *(u32*)(P + idx) = pk;
      }
  }

  f32x4 o[4][2] = {};
#pragma unroll
  for (int k0 = 0; k0 < 2; ++k0) {
    bf16x8 pa[4], vb[2];
#pragma unroll
    for (int qi = 0; qi < 4; ++qi) {
      int qq = qi * 16 + c;
      pa[qi] = *(const bf16x8*)(P + ((qq * 64 + k0 * 32 + g * 8) ^ ((qq & 7) << 3)));
    }
#pragma unroll
    for (int ni = 0; ni < 2; ++ni) {
      union { bf16x8 v; u16 a[8]; } vu;
#pragma unroll
      for (int e = 0; e < 8; ++e) {
        int j = k0 * 32 + g * 8 + e;
        int jr = j > 48 ? 48 : j;
        vu.a[e] = base[(size_t)jr * 1152 + 768 + ni * 16 + c];
      }
      vb[ni] = vu.v;
#pragma unroll
      for (int qi = 0; qi < 4; ++qi)
        o[qi][ni] = __builtin_amdgcn_mfma_f32_16x16x32_bf16(pa[qi], vb[ni],
                                                            o[qi][ni], 0, 0, 0);
    }
  }

  u16* ob = out + (size_t)n * 18816 + h * 32;
#pragma unroll
  for (int qi = 0; qi < 4; ++qi)
#pragma unroll
    for (int r = 0; r < 4; ++r) {
      int qq = qi * 16 + g * 4 + r;
      if (qq < 49) {
#pragma unroll
        for (int ni = 0; ni < 2; ++ni)
          ob[(size_t)qq * 384 + ni * 16 + c] = f2bf(o[qi][ni][r]);
      }
    }
}

// --------------------------------------------------------------------------
extern "C" void kernel_launch(void* const* d_in, const int* in_sizes, int n_in,
                              void* d_out, int out_size, void* d_ws,
                              size_t ws_size, hipStream_t stream) {
  const float* hidden = (const float*)d_in[0];
  const float* ln1g = (const float*)d_in[1];
  const float* ln1b = (const float*)d_in[2];
  const float* qkvw = (const float*)d_in[3];
  const float* qkvb = (const float*)d_in[4];
  const float* outw = (const float*)d_in[5];
  const float* outb = (const float*)d_in[6];
  const float* relt = (const float*)d_in[7];
  const float* ln2g = (const float*)d_in[8];
  const float* ln2b = (const float*)d_in[9];
  const float* fc1w = (const float*)d_in[10];
  const float* fc1b = (const float*)d_in[11];
  const float* fc2w = (const float*)d_in[12];
  const float* fc2b = (const float*)d_in[13];
  float* out = (float*)d_out;

  u16* wq = (u16*)d_ws;            // 1280*384 zero-padded (dead -> tbl)
  u16* wo = wq + 491520;           // 512*384 zero-padded
  u16* w1 = wo + 196608;           // 1536*384
  u16* w2 = w1 + 589824;           // 512*1536 zero-padded
  u16* xw = w2 + 786432;           // 100352*384  (also attn_out)
  u16* qkv = xw + 38535168;        // 100352*1152 (region reused below)
  u16* xn = qkv;                   // 100352*384
  u16* hbuf = xn + 38535168;       // 50176*1536 (row-half MLP buffer)
  float* tbl = (float*)wq;         // 196608 f32 <= wq region (245760 f32)

  k_f2bf<<<1920, 256, 0, stream>>>(qkvw, wq, 442368, 491520);
  k_f2bf<<<768, 256, 0, stream>>>(outw, wo, 147456, 196608);
  k_f2bf<<<2304, 256, 0, stream>>>(fc1w, w1, 589824, 589824);
  k_f2bf<<<3072, 256, 0, stream>>>(fc2w, w2, 589824, 786432);

  // LN1 + shift + window partition
  k_ln<1><<<25088, 256, 0, stream>>>(hidden, ln1g, ln1b, xw);

  // qkv = xw @ qkv_w^T + b  (q cols pre-scaled; N padded 1152->1280)
  k_gemm8<EPI_QKV><<<392 * 5, 512, 0, stream>>>(
      xw, wq, qkvb, qkv, nullptr, nullptr, 384, 384, 384, 1152, 5, 1152);

  // bias+mask tables into the now-dead wq region
  k_tbl<<<768, 256, 0, stream>>>(relt, tbl);

  // MFMA attention (writes attn_out into xw buffer)
  k_attn2<<<24576, 64, 0, stream>>>(qkv, tbl, xw);

  // out proj + window reverse + unshift + residual -> d_out (= x); N pad 512
  k_gemm8<EPI_PROJ><<<392 * 2, 512, 0, stream>>>(
      xw, wo, outb, nullptr, out, hidden, 384, 384, 384, 384, 2, 384);

  // LN2
  k_ln<0><<<25088, 256, 0, stream>>>(out, ln2g, ln2b, xn);

  // MLP, M-chunked (two row-halves), fc1 N=1536, fc2 K=1536 N pad 512
  for (int ch = 0; ch < 2; ++ch) {
    const u16* xa = xn + (size_t)ch * 50176 * 384;
    float* oc = out + (size_t)ch * 50176 * 384;
    k_gemm8<EPI_GELU><<<196 * 6, 512, 0, stream>>>(
        xa, w1, fc1b, hbuf, nullptr, nullptr, 384, 384, 384, 1536, 6, 1536);
    k_gemm8<EPI_FC2><<<196 * 2, 512, 0, stream>>>(
        hbuf, w2, fc2b, nullptr, oc, nullptr, 1536, 1536, 1536, 384, 2, 384);
  }
}

// Round 8
// 891.554 us; speedup vs baseline: 1.3506x; 1.3506x over previous
//
#include <hip/hip_runtime.h>
#include <cstdint>
#include <cstddef>

using u16 = unsigned short;
using u32 = unsigned int;

typedef __attribute__((ext_vector_type(8))) short bf16x8;
typedef __attribute__((ext_vector_type(4))) float f32x4;

__device__ __forceinline__ u16 f2bf(float f) {
  union { float f; u32 u; } v; v.f = f;
  u32 r = v.u + 0x7FFFu + ((v.u >> 16) & 1u);
  return (u16)(r >> 16);
}
__device__ __forceinline__ float bf2f(u16 h) {
  union { u32 u; float f; } v; v.u = ((u32)h) << 16;
  return v.f;
}

__device__ __forceinline__ void gl_lds16(const void* g, void* l) {
  __builtin_amdgcn_global_load_lds(
      (const __attribute__((address_space(1))) void*)g,
      (__attribute__((address_space(3))) void*)l, 16, 0, 0);
}

// ---------------- fp32 -> bf16 weight convert ----------------
__global__ __launch_bounds__(256) void k_f2bf(const float* __restrict__ s,
                                              u16* __restrict__ d, int n) {
  int i = blockIdx.x * 256 + threadIdx.x;
  if (i < n) d[i] = f2bf(s[i]);
}

// ---------------- combined rel-bias + shift-mask + pad tables ------------
// tbl[((h*4+wt))*4096 + j*64 + i]; wt = 2*(wh==7) + (ww==7); j>=49 -> -3e38
__global__ __launch_bounds__(256) void k_tbl(const float* __restrict__ relt,
                                             float* __restrict__ tbl) {
  int id = blockIdx.x * 256 + threadIdx.x;
  if (id >= 196608) return;
  int i = id & 63, j = (id >> 6) & 63;
  int wt = (id >> 12) & 3, h = id >> 14;
  float v;
  if (j >= 49) {
    v = -3e38f;
  } else {
    int ii = i < 49 ? i : 48;
    int r1 = ii / 7, c1 = ii % 7, r2 = j / 7, c2 = j % 7;
    v = relt[((r1 - r2 + 6) * 13 + (c1 - c2 + 6)) * 12 + h];
    int rr1 = (wt & 2) ? (r1 < 4 ? 1 : 2) : 0;
    int rr2 = (wt & 2) ? (r2 < 4 ? 1 : 2) : 0;
    int cc1 = (wt & 1) ? (c1 < 4 ? 1 : 2) : 0;
    int cc2 = (wt & 1) ? (c2 < 4 ? 1 : 2) : 0;
    if (rr1 != rr2 || cc1 != cc2) v -= 100.f;
  }
  tbl[id] = v;
}

// ---------------- LayerNorm (optionally fused shift+window gather) -------
template <int GATHER>
__global__ __launch_bounds__(256) void k_ln(const float* __restrict__ x,
                                            const float* __restrict__ g,
                                            const float* __restrict__ b,
                                            u16* __restrict__ out) {
  int wave = threadIdx.x >> 6, lane = threadIdx.x & 63;
  int idx = blockIdx.x * 4 + wave;  // output token index
  int src;
  if (GATHER) {
    int n = idx / 49, l = idx % 49;
    int bb = n >> 6, wi = n & 63;
    int wh = wi >> 3, ww = wi & 7;
    int r = l / 7, c = l % 7;
    int sr = wh * 7 + r + 3; if (sr >= 56) sr -= 56;
    int sc = ww * 7 + c + 3; if (sc >= 56) sc -= 56;
    src = bb * 3136 + sr * 56 + sc;
  } else {
    src = idx;
  }
  const float* xi = x + (size_t)src * 384;
  float2 v[3];
  float s = 0.f, sq = 0.f;
#pragma unroll
  for (int p = 0; p < 3; ++p) {
    v[p] = *(const float2*)(xi + p * 128 + lane * 2);
    s += v[p].x + v[p].y;
    sq += v[p].x * v[p].x + v[p].y * v[p].y;
  }
#pragma unroll
  for (int o = 32; o; o >>= 1) {
    s += __shfl_xor(s, o);
    sq += __shfl_xor(sq, o);
  }
  float mu = s * (1.f / 384.f);
  float var = sq * (1.f / 384.f) - mu * mu;
  float rstd = rsqrtf(var + 1e-5f);
  u16* oo = out + (size_t)idx * 384;
#pragma unroll
  for (int p = 0; p < 3; ++p) {
    int e = p * 128 + lane * 2;
    u16 o0 = f2bf((v[p].x - mu) * rstd * g[e] + b[e]);
    u16 o1 = f2bf((v[p].y - mu) * rstd * g[e + 1] + b[e + 1]);
    u32 pk = (u32)o0 | ((u32)o1 << 16);
    *(u32*)(oo + e) = pk;
  }
}

// ---------------- GEMM v4: 256x128 tile, 8 waves, BK=64, single-buffer ----
// m97-class loop (stage -> __syncthreads -> compute -> __syncthreads): the
// vmcnt(0) drain inside __syncthreads is hidden by 3 blocks/CU (48KB LDS).
// T2 XOR-swizzle both-sides (pre-swizzled global source for gl_lds, XOR'd
// ds_read) -> 0 bank conflicts. XCD chunk swizzle (n-inner) for A L2 reuse.
enum { EPI_QKV = 0, EPI_PROJ = 1, EPI_GELU = 2, EPI_FC2 = 3 };

template <int EPI>
__global__ __launch_bounds__(512, 2) void k_gemm3(
    const u16* __restrict__ A, const u16* __restrict__ Bw,
    const float* __restrict__ bias, u16* __restrict__ obf,
    float* __restrict__ of32, const float* __restrict__ addsrc,
    int K, int lda, int ldb, int ldc, int NT) {
  __shared__ u16 As[256 * 64];  // 32 KB
  __shared__ u16 Bs[128 * 64];  // 16 KB
  // bijective XCD chunk swizzle (m204), n-inner for A-panel L2 reuse
  const int nwg = gridDim.x;
  const int q = nwg >> 3, r = nwg & 7;
  const int xcd = blockIdx.x & 7, rank = blockIdx.x >> 3;
  const int swz = (xcd < r ? xcd * (q + 1) : r * (q + 1) + (xcd - r) * q) + rank;
  const int m0 = (swz / NT) * 256, n0 = (swz % NT) * 128;

  const int tid = threadIdx.x;
  const int wid = tid >> 6, lane = tid & 63;
  const int wr = wid >> 1, wc = wid & 1;  // 4M x 2N waves, per-wave 64x64

  // staging: pre-swizzled global source; linear LDS dest (HW adds lane*16B)
  const int srow = tid >> 3;                      // 0..63
  const int scol = 8 * ((tid & 7) ^ (srow & 7));  // inverse-swizzled col
  const size_t abase = (size_t)(m0 + srow) * lda + scol;
  const size_t bbase = (size_t)(n0 + srow) * ldb + scol;
  const int dbase = wid * 512;  // (wid*8 rows)*64 u16

  f32x4 acc[4][4] = {};
  const int lrow = lane & 15;
  const int g8 = (lane >> 4) * 8;
  const int rx = (lrow & 7) << 3;  // read-side XOR (u16 units)

  const int NTK = K >> 6;

  for (int t = 0; t < NTK; ++t) {
    const int k0 = t << 6;
    // stage A (4 x 64-row slabs) + B (2 slabs)
#pragma unroll
    for (int i = 0; i < 4; ++i)
      gl_lds16(A + abase + (size_t)(i * 64) * lda + k0,
               As + i * 4096 + dbase);
#pragma unroll
    for (int i = 0; i < 2; ++i)
      gl_lds16(Bw + bbase + (size_t)(i * 64) * ldb + k0,
               Bs + i * 4096 + dbase);
    __syncthreads();  // drains vmcnt/lgkm + barrier (known semantics)
    __builtin_amdgcn_s_setprio(1);
#pragma unroll
    for (int kk = 0; kk < 64; kk += 32) {
      bf16x8 af[4], bf[4];
#pragma unroll
      for (int mi = 0; mi < 4; ++mi) {
        int row = wr * 64 + mi * 16 + lrow;
        af[mi] = *(const bf16x8*)(&As[row * 64 + ((kk + g8) ^ rx)]);
      }
#pragma unroll
      for (int ni = 0; ni < 4; ++ni) {
        int row = wc * 64 + ni * 16 + lrow;
        bf[ni] = *(const bf16x8*)(&Bs[row * 64 + ((kk + g8) ^ rx)]);
      }
#pragma unroll
      for (int mi = 0; mi < 4; ++mi)
#pragma unroll
        for (int ni = 0; ni < 4; ++ni)
          acc[mi][ni] = __builtin_amdgcn_mfma_f32_16x16x32_bf16(
              af[mi], bf[ni], acc[mi][ni], 0, 0, 0);
    }
    __builtin_amdgcn_s_setprio(0);
    __syncthreads();  // protect buffers before next stage
  }

  // epilogue: D mapping col=lane&15, row=(lane>>4)*4+reg
  const int erow = (lane >> 4) * 4;
  const int ecol = lane & 15;
#pragma unroll
  for (int mi = 0; mi < 4; ++mi) {
#pragma unroll
    for (int ni = 0; ni < 4; ++ni) {
      int gcol = n0 + wc * 64 + ni * 16 + ecol;
      float bv = bias[gcol];
#pragma unroll
      for (int r4 = 0; r4 < 4; ++r4) {
        int grow = m0 + wr * 64 + mi * 16 + erow + r4;
        float v = acc[mi][ni][r4] + bv;
        if (EPI == EPI_QKV) {
          // fold attention scale 1/sqrt(32) into q columns (cols < 384)
          float vv = (gcol < 384) ? v * 0.17677669529663689f : v;
          obf[(size_t)grow * ldc + gcol] = f2bf(vv);
        } else if (EPI == EPI_GELU) {
          float gl = 0.5f * v * (1.f + erff(v * 0.70710678118f));
          obf[(size_t)grow * ldc + gcol] = f2bf(gl);
        } else if (EPI == EPI_PROJ) {
          int nwin = grow / 49, l = grow % 49;
          int bb = nwin >> 6, wi = nwin & 63;
          int wh = wi >> 3, ww = wi & 7;
          int rr = l / 7, cc = l % 7;
          int sr = wh * 7 + rr + 3; if (sr >= 56) sr -= 56;
          int sc = ww * 7 + cc + 3; if (sc >= 56) sc -= 56;
          size_t idx = ((size_t)(bb * 3136 + sr * 56 + sc)) * 384 + gcol;
          of32[idx] = addsrc[idx] + v;
        } else {  // EPI_FC2: accumulate into (row-chunked) d_out
          size_t idx = (size_t)grow * 384 + gcol;
          of32[idx] = of32[idx] + v;
        }
      }
    }
  }
}

// ---------------- MFMA windowed attention v2 ------------------------------
__global__ __launch_bounds__(64) void k_attn2(const u16* __restrict__ qkv,
                                              const float* __restrict__ tbl,
                                              u16* __restrict__ out) {
  __shared__ u16 P[64 * 64];  // 8KB, wave-private
  const int bx = blockIdx.x;
  const int n = bx / 12, h = bx - n * 12;
  const int lane = threadIdx.x & 63;
  const int g = lane >> 4, c = lane & 15;
  const u16* base = qkv + (size_t)n * 56448 + h * 32;
  const int wi = n & 63;
  const int wt = (((wi >> 3) == 7) ? 2 : 0) | (((wi & 7) == 7) ? 1 : 0);
  const float* T = tbl + (size_t)((h << 2) | wt) * 4096;

  f32x4 st[4][4];  // [kj][qi]; reg r -> j = kj*16+g*4+r, i = qi*16+c
#pragma unroll
  for (int kj = 0; kj < 4; ++kj)
#pragma unroll
    for (int qi = 0; qi < 4; ++qi)
#pragma unroll
      for (int r = 0; r < 4; ++r)
        st[kj][qi][r] = T[(kj * 16 + g * 4 + r) * 64 + qi * 16 + c];

  bf16x8 qf[4], kf[4];
#pragma unroll
  for (int t = 0; t < 4; ++t) {
    int row = t * 16 + c; if (row > 48) row = 48;
    qf[t] = *(const bf16x8*)(base + (size_t)row * 1152 + g * 8);
    kf[t] = *(const bf16x8*)(base + (size_t)row * 1152 + 384 + g * 8);
  }

#pragma unroll
  for (int kj = 0; kj < 4; ++kj)
#pragma unroll
    for (int qi = 0; qi < 4; ++qi)
      st[kj][qi] = __builtin_amdgcn_mfma_f32_16x16x32_bf16(kf[kj], qf[qi],
                                                           st[kj][qi], 0, 0, 0);

#pragma unroll
  for (int qi = 0; qi < 4; ++qi) {
    float m = -3e38f;
#pragma unroll
    for (int kj = 0; kj < 4; ++kj)
#pragma unroll
      for (int r = 0; r < 4; ++r) m = fmaxf(m, st[kj][qi][r]);
    m = fmaxf(m, __shfl_xor(m, 16));
    m = fmaxf(m, __shfl_xor(m, 32));
    float sum = 0.f;
#pragma unroll
    for (int kj = 0; kj < 4; ++kj)
#pragma unroll
      for (int r = 0; r < 4; ++r) {
        float e = __expf(st[kj][qi][r] - m);
        st[kj][qi][r] = e;
        sum += e;
      }
    sum += __shfl_xor(sum, 16);
    sum += __shfl_xor(sum, 32);
    float inv = 1.f / sum;
    int i = qi * 16 + c;
#pragma unroll
    for (int kj = 0; kj < 4; ++kj)
#pragma unroll
      for (int hh = 0; hh < 2; ++hh) {
        u32 pk = (u32)f2bf(st[kj][qi][2 * hh] * inv) |
                 ((u32)f2bf(st[kj][qi][2 * hh + 1] * inv) << 16);
        int idx = (i * 64 + kj * 16 + g * 4 + 2 * hh) ^ ((i & 7) << 3);
        *(u32*)(P + idx) = pk;
      }
  }

  f32x4 o[4][2] = {};
#pragma unroll
  for (int k0 = 0; k0 < 2; ++k0) {
    bf16x8 pa[4], vb[2];
#pragma unroll
    for (int qi = 0; qi < 4; ++qi) {
      int qq = qi * 16 + c;
      pa[qi] = *(const bf16x8*)(P + ((qq * 64 + k0 * 32 + g * 8) ^ ((qq & 7) << 3)));
    }
#pragma unroll
    for (int ni = 0; ni < 2; ++ni) {
      union { bf16x8 v; u16 a[8]; } vu;
#pragma unroll
      for (int e = 0; e < 8; ++e) {
        int j = k0 * 32 + g * 8 + e;
        int jr = j > 48 ? 48 : j;
        vu.a[e] = base[(size_t)jr * 1152 + 768 + ni * 16 + c];
      }
      vb[ni] = vu.v;
#pragma unroll
      for (int qi = 0; qi < 4; ++qi)
        o[qi][ni] = __builtin_amdgcn_mfma_f32_16x16x32_bf16(pa[qi], vb[ni],
                                                            o[qi][ni], 0, 0, 0);
    }
  }

  u16* ob = out + (size_t)n * 18816 + h * 32;
#pragma unroll
  for (int qi = 0; qi < 4; ++qi)
#pragma unroll
    for (int r = 0; r < 4; ++r) {
      int qq = qi * 16 + g * 4 + r;
      if (qq < 49) {
#pragma unroll
        for (int ni = 0; ni < 2; ++ni)
          ob[(size_t)qq * 384 + ni * 16 + c] = f2bf(o[qi][ni][r]);
      }
    }
}

// --------------------------------------------------------------------------
extern "C" void kernel_launch(void* const* d_in, const int* in_sizes, int n_in,
                              void* d_out, int out_size, void* d_ws,
                              size_t ws_size, hipStream_t stream) {
  const float* hidden = (const float*)d_in[0];
  const float* ln1g = (const float*)d_in[1];
  const float* ln1b = (const float*)d_in[2];
  const float* qkvw = (const float*)d_in[3];
  const float* qkvb = (const float*)d_in[4];
  const float* outw = (const float*)d_in[5];
  const float* outb = (const float*)d_in[6];
  const float* relt = (const float*)d_in[7];
  const float* ln2g = (const float*)d_in[8];
  const float* ln2b = (const float*)d_in[9];
  const float* fc1w = (const float*)d_in[10];
  const float* fc1b = (const float*)d_in[11];
  const float* fc2w = (const float*)d_in[12];
  const float* fc2b = (const float*)d_in[13];
  float* out = (float*)d_out;

  u16* wq = (u16*)d_ws;            // 1152*384 (dead after qkv GEMM -> tbl)
  u16* wo = wq + 442368;           // 384*384
  u16* w1 = wo + 147456;           // 1536*384
  u16* w2 = w1 + 589824;           // 384*1536
  u16* xw = w2 + 589824;           // 100352*384  (also attn_out)
  u16* qkv = xw + 38535168;        // 100352*1152 (region reused below)
  u16* xn = qkv;                   // 100352*384
  u16* hbuf = xn + 38535168;       // 50176*1536 (row-half MLP buffer)
  float* tbl = (float*)wq;         // 196608 f32 <= wq region (221184 f32)

  k_f2bf<<<1728, 256, 0, stream>>>(qkvw, wq, 442368);
  k_f2bf<<<576, 256, 0, stream>>>(outw, wo, 147456);
  k_f2bf<<<2304, 256, 0, stream>>>(fc1w, w1, 589824);
  k_f2bf<<<2304, 256, 0, stream>>>(fc2w, w2, 589824);

  // LN1 + shift + window partition
  k_ln<1><<<25088, 256, 0, stream>>>(hidden, ln1g, ln1b, xw);

  // qkv = xw @ qkv_w^T + b  (q cols pre-scaled by 1/sqrt(32))
  k_gemm3<EPI_QKV><<<392 * 9, 512, 0, stream>>>(
      xw, wq, qkvb, qkv, nullptr, nullptr, 384, 384, 384, 1152, 9);

  // bias+mask tables into the now-dead wq region
  k_tbl<<<768, 256, 0, stream>>>(relt, tbl);

  // MFMA attention (writes attn_out into xw buffer)
  k_attn2<<<24576, 64, 0, stream>>>(qkv, tbl, xw);

  // out proj + window reverse + unshift + residual -> d_out (= x)
  k_gemm3<EPI_PROJ><<<392 * 3, 512, 0, stream>>>(
      xw, wo, outb, nullptr, out, hidden, 384, 384, 384, 384, 3);

  // LN2
  k_ln<0><<<25088, 256, 0, stream>>>(out, ln2g, ln2b, xn);

  // MLP, M-chunked (two row-halves), full N=1536 / K=1536
  for (int ch = 0; ch < 2; ++ch) {
    const u16* xa = xn + (size_t)ch * 50176 * 384;
    float* oc = out + (size_t)ch * 50176 * 384;
    k_gemm3<EPI_GELU><<<196 * 12, 512, 0, stream>>>(
        xa, w1, fc1b, hbuf, nullptr, nullptr, 384, 384, 384, 1536, 12);
    k_gemm3<EPI_FC2><<<196 * 3, 512, 0, stream>>>(
        hbuf, w2, fc2b, nullptr, oc, nullptr, 1536, 1536, 1536, 384, 3);
  }
}